// Round 6
// baseline (208.839 us; speedup 1.0000x reference)
//
#include <hip/hip_runtime.h>
#include <math.h>

#define B 32
#define N 512
#define DIN 768
#define DOUT 256
#define NEGV -9.0e15f
#define SLOPE 0.2f

typedef __bf16 bf16x8 __attribute__((ext_vector_type(8)));
typedef float f32x4 __attribute__((ext_vector_type(4)));
typedef unsigned short us8 __attribute__((ext_vector_type(8)));   // 16 B

__device__ __forceinline__ unsigned short f2b(float f) {
    union { float f; unsigned u; } v; v.f = f;
    unsigned r = v.u + 0x7FFF + ((v.u >> 16) & 1);
    return (unsigned short)(r >> 16);
}

__device__ __forceinline__ bf16x8 cvt8(float4 a, float4 b) {
    bf16x8 v;
    v[0] = (__bf16)a.x; v[1] = (__bf16)a.y; v[2] = (__bf16)a.z; v[3] = (__bf16)a.w;
    v[4] = (__bf16)b.x; v[5] = (__bf16)b.y; v[6] = (__bf16)b.z; v[7] = (__bf16)b.w;
    return v;
}

// ---------------------------------------------------------------------------
// W [768][256] fp32 -> WT [256][768] bf16, LDS-transposed 64x64 tiles.
// ---------------------------------------------------------------------------
__global__ __launch_bounds__(256) void conv_wt(const float* __restrict__ W,
                                               unsigned short* __restrict__ WT) {
    __shared__ unsigned short tile[64][65];
    const int k0 = blockIdx.x * 64, n0 = blockIdx.y * 64;
    const int t = threadIdx.x;
    const int cl = t & 63, cg = t >> 6;
#pragma unroll
    for (int i = 0; i < 16; ++i) {
        int k = cg * 16 + i;
        tile[cl][k] = f2b(W[(size_t)(k0 + k) * DOUT + n0 + cl]);
    }
    __syncthreads();
#pragma unroll
    for (int i = 0; i < 16; ++i) {
        int n = cg * 16 + i;
        WT[(size_t)(n0 + n) * DIN + k0 + cl] = tile[n][cl];
    }
}

// ---------------------------------------------------------------------------
// GEMM1: Wh = h @ W + pos_emb -> WhT[b][d][j] bf16 (n-major), fused s1/s2.
// Tile 128m x 64n, 256 thr (4 waves, each 64m x 32n).
// BARRIER-FREE K-loop: A-frags read straight from fp32 h (inline cvt),
// B-frags straight from bf16 WT (L2-resident). LDS only for the epilogue
// transpose tile.
// ---------------------------------------------------------------------------
__global__ __launch_bounds__(256) void wh_mfma(
    const float* __restrict__ hA,            // [16384][768] fp32
    const unsigned short* __restrict__ WT,   // [256][768] bf16
    const int*   __restrict__ pos,           // [16384]
    const float* __restrict__ ptab,          // [512][256]
    const float* __restrict__ a1,
    const float* __restrict__ a2,
    unsigned short* __restrict__ WhT,        // [32][256][512]
    float* __restrict__ s1, float* __restrict__ s2)
{
    constexpr int K = DIN;
    __shared__ unsigned short tileT[64 * 136];   // 17.4 KB transpose buffer

    const int t    = threadIdx.x;
    const int lane = t & 63;
    const int w    = t >> 6;
    const int lin  = blockIdx.x;
    const int m0   = (lin & 127) * 128;
    const int n0   = (lin >> 7) * 64;

    const int wm = (w & 1) * 64, wn = (w >> 1) * 32;
    const int l15 = lane & 15, q = lane >> 4;

    // fragment source pointers (A: fp32 h rows; B: bf16 WT rows)
    const float* aRow[4];
#pragma unroll
    for (int mi = 0; mi < 4; ++mi)
        aRow[mi] = hA + (size_t)(m0 + wm + mi * 16 + l15) * DIN + q * 8;
    const unsigned short* bRow[2];
#pragma unroll
    for (int ni = 0; ni < 2; ++ni)
        bRow[ni] = WT + (size_t)(n0 + wn + ni * 16 + l15) * DIN + q * 8;

    f32x4 acc[4][2];
#pragma unroll
    for (int i = 0; i < 4; ++i)
#pragma unroll
        for (int j = 0; j < 2; ++j) acc[i][j] = (f32x4){0.f, 0.f, 0.f, 0.f};

#pragma unroll 4
    for (int k0 = 0; k0 < K; k0 += 32) {
        bf16x8 af[4], bfr[2];
#pragma unroll
        for (int mi = 0; mi < 4; ++mi) {
            const float4* ap = (const float4*)(aRow[mi] + k0);
            af[mi] = cvt8(ap[0], ap[1]);
        }
#pragma unroll
        for (int ni = 0; ni < 2; ++ni)
            bfr[ni] = *(const bf16x8*)(bRow[ni] + k0);
#pragma unroll
        for (int mi = 0; mi < 4; ++mi)
#pragma unroll
            for (int ni = 0; ni < 2; ++ni)
                acc[mi][ni] = __builtin_amdgcn_mfma_f32_16x16x32_bf16(
                    af[mi], bfr[ni], acc[mi][ni], 0, 0, 0);
    }

    // epilogue: + pos_emb; fused s1/s2 partials; transpose tile; coalesced write
    const float a1v[2] = { a1[n0 + wn + l15], a1[n0 + wn + 16 + l15] };
    const float a2v[2] = { a2[n0 + wn + l15], a2[n0 + wn + 16 + l15] };
#pragma unroll
    for (int mi = 0; mi < 4; ++mi) {
        const int jb = wm + mi * 16 + q * 4;
        float v[2][4];
#pragma unroll
        for (int ni = 0; ni < 2; ++ni) {
            const int nl = wn + ni * 16 + l15;
            ushort4 pk;
            unsigned short* pp = (unsigned short*)&pk;
#pragma unroll
            for (int r = 0; r < 4; ++r) {
                int m = m0 + jb + r;
                int p = pos[m];
                float val = acc[mi][ni][r] + ptab[(size_t)p * DOUT + n0 + nl];
                v[ni][r] = val;
                pp[r] = f2b(val);
            }
            *(ushort4*)&tileT[nl * 136 + jb] = pk;
        }
#pragma unroll
        for (int r = 0; r < 4; ++r) {
            float t1 = v[0][r] * a1v[0] + v[1][r] * a1v[1];
            float t2 = v[0][r] * a2v[0] + v[1][r] * a2v[1];
#pragma unroll
            for (int mk = 1; mk < 16; mk <<= 1) {
                t1 += __shfl_xor(t1, mk);
                t2 += __shfl_xor(t2, mk);
            }
            if (l15 == 0) {
                atomicAdd(&s1[m0 + jb + r], t1);
                atomicAdd(&s2[m0 + jb + r], t2);
            }
        }
    }
    __syncthreads();
    const int bb = m0 >> 9, j0 = m0 & 511;
#pragma unroll
    for (int rr = 0; rr < 4; ++rr) {
        int nl = (t >> 4) + rr * 16;
        int jl = (t & 15) * 8;
        us8 vv = *(const us8*)&tileT[nl * 136 + jl];
        *(us8*)&WhT[((size_t)bb * DOUT + n0 + nl) * N + j0 + jl] = vv;
    }
}

// ---------------------------------------------------------------------------
// Fused softmax + GEMM2.  One block per (b, 64-row m-tile); 512 threads.
// Phase 1: masked softmax for 64 rows (8 lanes/row), writes att fp32 (output)
//          and deposits P bf16 into swizzled LDS (A-operand layout).
// Phase 2: barrier-free K=512 MFMA loop, B-frags direct from WhT (n-major).
// P LDS layout: addr(r,k) = r*512 + S*8 + (k&7), slot=k>>3,
//               S = slot ^ (r&7) ^ (slot>>3).
// ---------------------------------------------------------------------------
__global__ __launch_bounds__(512) void attn_hp(
    const float* __restrict__ s1,
    const float* __restrict__ s2,
    const int*   __restrict__ adj,
    const unsigned short* __restrict__ WhT,  // [32][256][512]
    float* __restrict__ att,                 // [32][512][512]
    float* __restrict__ hp)                  // [32][512][256]
{
    __shared__ unsigned short P[64 * 512];   // 64 KB

    const int t    = threadIdx.x;
    const int lane = t & 63;
    const int w    = t >> 6;
    const int bb   = blockIdx.x >> 3;
    const int m0   = (blockIdx.x & 7) * 64;

    // ---- phase 1: softmax over 64 rows; 8 threads per row, 64 cols each ----
    {
        const int r = t >> 3, c = t & 7;
        const size_t rowg = (size_t)bb * N + m0 + r;
        const float s1i = s1[rowg];
        const int4*   adjp = (const int4*)(adj + rowg * N + c * 64);
        const float4* s2p  = (const float4*)(s2 + (size_t)bb * N + c * 64);
        float fe[64];
        float mx = -3.0e38f;
#pragma unroll
        for (int i = 0; i < 16; ++i) {
            int4 a = adjp[i];
            float4 sv = s2p[i];
            float v0 = s1i + sv.x; v0 = v0 > 0.f ? v0 : SLOPE * v0; v0 = (a.x > 0) ? v0 : NEGV;
            float v1 = s1i + sv.y; v1 = v1 > 0.f ? v1 : SLOPE * v1; v1 = (a.y > 0) ? v1 : NEGV;
            float v2 = s1i + sv.z; v2 = v2 > 0.f ? v2 : SLOPE * v2; v2 = (a.z > 0) ? v2 : NEGV;
            float v3 = s1i + sv.w; v3 = v3 > 0.f ? v3 : SLOPE * v3; v3 = (a.w > 0) ? v3 : NEGV;
            fe[i * 4 + 0] = v0; fe[i * 4 + 1] = v1;
            fe[i * 4 + 2] = v2; fe[i * 4 + 3] = v3;
            mx = fmaxf(mx, fmaxf(fmaxf(v0, v1), fmaxf(v2, v3)));
        }
#pragma unroll
        for (int mk = 1; mk < 8; mk <<= 1) mx = fmaxf(mx, __shfl_xor(mx, mk));
        float sum = 0.f;
#pragma unroll
        for (int k = 0; k < 64; ++k) { fe[k] = __expf(fe[k] - mx); sum += fe[k]; }
#pragma unroll
        for (int mk = 1; mk < 8; mk <<= 1) sum += __shfl_xor(sum, mk);
        const float inv = 1.0f / sum;

        float* attrow = att + rowg * N + c * 64;
#pragma unroll
        for (int i = 0; i < 16; ++i) {
            float4 o = { fe[i * 4 + 0] * inv, fe[i * 4 + 1] * inv,
                         fe[i * 4 + 2] * inv, fe[i * 4 + 3] * inv };
            ((float4*)attrow)[i] = o;
        }
#pragma unroll
        for (int jj = 0; jj < 8; ++jj) {
            int slot = c * 8 + jj;
            int S = slot ^ (r & 7) ^ c;          // c == slot>>3
            bf16x8 pv;
#pragma unroll
            for (int e = 0; e < 8; ++e) pv[e] = (__bf16)(fe[jj * 8 + e] * inv);
            *(bf16x8*)&P[r * 512 + S * 8] = pv;
        }
    }
    __syncthreads();

    // ---- phase 2: hp[m0..m0+64][0..256] = P @ WhT^T, K = 512 ----
    const int wn  = w * 32;
    const int l15 = lane & 15, q = lane >> 4;
    const unsigned short* bRow[2];
#pragma unroll
    for (int ni = 0; ni < 2; ++ni)
        bRow[ni] = WhT + ((size_t)bb * DOUT + wn + ni * 16 + l15) * N + q * 8;
    int rm7[4], rmBase[4];
#pragma unroll
    for (int mi = 0; mi < 4; ++mi) {
        int rm = mi * 16 + l15;
        rm7[mi] = rm & 7;
        rmBase[mi] = rm * 512;
    }

    f32x4 acc[4][2];
#pragma unroll
    for (int i = 0; i < 4; ++i)
#pragma unroll
        for (int j = 0; j < 2; ++j) acc[i][j] = (f32x4){0.f, 0.f, 0.f, 0.f};

#pragma unroll 4
    for (int k0 = 0; k0 < N; k0 += 32) {
        const int slot = (k0 >> 3) + q;          // 0..63
        const int hi = slot >> 3;
        bf16x8 af[4], bfr[2];
#pragma unroll
        for (int ni = 0; ni < 2; ++ni)
            bfr[ni] = *(const bf16x8*)(bRow[ni] + k0);
#pragma unroll
        for (int mi = 0; mi < 4; ++mi) {
            int S = slot ^ rm7[mi] ^ hi;
            af[mi] = *(const bf16x8*)&P[rmBase[mi] + S * 8];
        }
#pragma unroll
        for (int mi = 0; mi < 4; ++mi)
#pragma unroll
            for (int ni = 0; ni < 2; ++ni)
                acc[mi][ni] = __builtin_amdgcn_mfma_f32_16x16x32_bf16(
                    af[mi], bfr[ni], acc[mi][ni], 0, 0, 0);
    }

#pragma unroll
    for (int mi = 0; mi < 4; ++mi) {
#pragma unroll
        for (int rr = 0; rr < 4; ++rr) {
            int m = m0 + mi * 16 + q * 4 + rr;
#pragma unroll
            for (int ni = 0; ni < 2; ++ni) {
                int n = wn + ni * 16 + l15;
                hp[((size_t)bb * N + m) * DOUT + n] = acc[mi][ni][rr];
            }
        }
    }
}

// ---------------------------------------------------------------------------
extern "C" void kernel_launch(void* const* d_in, const int* in_sizes, int n_in,
                              void* d_out, int out_size, void* d_ws, size_t ws_size,
                              hipStream_t stream) {
    const float* h         = (const float*)d_in[0];
    const int*   adj       = (const int*)  d_in[1];
    const int*   positions = (const int*)  d_in[2];
    const float* W         = (const float*)d_in[3];
    const float* a1        = (const float*)d_in[4];
    const float* a2        = (const float*)d_in[5];
    const float* pos_table = (const float*)d_in[6];

    float* out     = (float*)d_out;
    float* h_prime = out;                           // [B,N,DOUT]
    float* att     = out + (size_t)B * N * DOUT;    // [B,N,N]

    char* ws = (char*)d_ws;
    unsigned short* WT  = (unsigned short*)ws;                 // 393216 B
    unsigned short* WhT = (unsigned short*)(ws + 0x100000);    // 8.39 MB
    float*          s1  = (float*)(ws + 0x900000);             // 64 KB
    float*          s2  = s1 + (size_t)B * N;

    // 0) zero s1/s2 for the fused atomics
    hipMemsetAsync(s1, 0, (size_t)2 * B * N * sizeof(float), stream);
    // 1) W -> WT bf16 (LDS transpose)
    {
        dim3 grid(DIN / 64, DOUT / 64);
        conv_wt<<<grid, 256, 0, stream>>>(W, WT);
    }
    // 2) Wh GEMM (barrier-free, fp32-A direct) + pos_emb -> WhT bf16, fused s1/s2
    wh_mfma<<<512, 256, 0, stream>>>(h, WT, positions, pos_table, a1, a2, WhT, s1, s2);
    // 3) fused softmax + h_prime GEMM
    attn_hp<<<256, 512, 0, stream>>>(s1, s2, adj, WhT, att, h_prime);
}

// Round 7
// 172.980 us; speedup vs baseline: 1.2073x; 1.2073x over previous
//
#include <hip/hip_runtime.h>
#include <math.h>

#define B 32
#define N 512
#define DIN 768
#define DOUT 256
#define NEGV -9.0e15f
#define SLOPE 0.2f

typedef __bf16 bf16x8 __attribute__((ext_vector_type(8)));
typedef float f32x4 __attribute__((ext_vector_type(4)));
typedef unsigned short us8 __attribute__((ext_vector_type(8)));   // 16 B

__device__ __forceinline__ unsigned short f2b(float f) {
    union { float f; unsigned u; } v; v.f = f;
    unsigned r = v.u + 0x7FFF + ((v.u >> 16) & 1);
    return (unsigned short)(r >> 16);
}

// async 16B/lane global->LDS; lds ptr wave-uniform (lane i lands at base+i*16)
__device__ __forceinline__ void gload_lds16(const unsigned short* g, unsigned short* l) {
    __builtin_amdgcn_global_load_lds(
        (const __attribute__((address_space(1))) unsigned int*)(unsigned long long)(uintptr_t)g,
        (__attribute__((address_space(3))) unsigned int*)(uintptr_t)l,
        16, 0, 0);
}

// ---------------------------------------------------------------------------
// fused: blocks [0,12288) convert h fp32->bf16 (4/thr);
//        blocks [12288,12336) transpose W -> WT bf16 (64x64 LDS tiles)
// ---------------------------------------------------------------------------
__global__ __launch_bounds__(256) void conv_fused(
    const float4* __restrict__ hin, ushort4* __restrict__ hout,
    const float* __restrict__ W, unsigned short* __restrict__ WT) {
    __shared__ unsigned short tile[64][65];
    const int t = threadIdx.x;
    if (blockIdx.x < 12288) {
        int idx = blockIdx.x * 256 + t;
        float4 v = hin[idx];
        ushort4 o;
        o.x = f2b(v.x); o.y = f2b(v.y); o.z = f2b(v.z); o.w = f2b(v.w);
        hout[idx] = o;
    } else {
        int bid = blockIdx.x - 12288;
        int k0 = (bid % 12) * 64, n0 = (bid / 12) * 64;
        const int cl = t & 63, cg = t >> 6;
#pragma unroll
        for (int i = 0; i < 16; ++i) {
            int k = cg * 16 + i;
            tile[cl][k] = f2b(W[(size_t)(k0 + k) * DOUT + n0 + cl]);
        }
        __syncthreads();
#pragma unroll
        for (int i = 0; i < 16; ++i) {
            int n = cg * 16 + i;
            WT[(size_t)(n0 + n) * DIN + k0 + cl] = tile[n][cl];
        }
    }
}

// ---------------------------------------------------------------------------
// GEMM1: Wh = h @ W + pos_emb -> WhT[b][d][j] bf16 (n-major), fused s1/s2.
// Tile 128m x 64n, BK=64, 256 thr (4 waves, each 64m x 32n). LDS-staged
// (global_load_lds w=16), XOR-swizzled. 1-D grid 512: m-tile = lin&127.
// ---------------------------------------------------------------------------
__global__ __launch_bounds__(256) void wh_mfma(
    const unsigned short* __restrict__ hA,   // [16384][768] bf16
    const unsigned short* __restrict__ WT,   // [256][768] bf16
    const int*   __restrict__ pos,           // [16384]
    const float* __restrict__ ptab,          // [512][256]
    const float* __restrict__ a1,
    const float* __restrict__ a2,
    unsigned short* __restrict__ WhT,        // [32][256][512]
    float* __restrict__ s1, float* __restrict__ s2)
{
    constexpr int K = DIN;
    // As: 128 rows x 64k = 8192 shorts; Bs: 64 x 64 = 4096; tileT overlays
    __shared__ unsigned short smem[12288];
    unsigned short* As = smem;
    unsigned short* Bs = smem + 8192;
    unsigned short* tileT = smem;            // reused after k-loop

    const int t    = threadIdx.x;
    const int lane = t & 63;
    const int w    = t >> 6;
    const int lin  = blockIdx.x;
    const int m0   = (lin & 127) * 128;
    const int n0   = (lin >> 7) * 64;

    // staging chunk maps: chunk c -> row r = c>>3, lds slot s = c&7, global pg = s^(r&7)
    int arow[4], apos[4];
#pragma unroll
    for (int i = 0; i < 4; ++i) {
        int c = i * 256 + t;
        arow[i] = c >> 3;
        apos[i] = (c & 7) ^ ((c >> 3) & 7);
    }
    int brow[2], bpos[2];
#pragma unroll
    for (int i = 0; i < 2; ++i) {
        int c = i * 256 + t;
        brow[i] = c >> 3;
        bpos[i] = (c & 7) ^ ((c >> 3) & 7);
    }
    const unsigned short* gA[4];
    const unsigned short* gB[2];
#pragma unroll
    for (int i = 0; i < 4; ++i) gA[i] = hA + (size_t)(m0 + arow[i]) * K + apos[i] * 8;
#pragma unroll
    for (int i = 0; i < 2; ++i) gB[i] = WT + (size_t)(n0 + brow[i]) * K + bpos[i] * 8;
    unsigned short* lA[4];
    unsigned short* lB[2];
#pragma unroll
    for (int i = 0; i < 4; ++i) lA[i] = As + (i * 256 + (t & 192)) * 8;
#pragma unroll
    for (int i = 0; i < 2; ++i) lB[i] = Bs + (i * 256 + (t & 192)) * 8;

    const int wm = (w & 1) * 64, wn = (w >> 1) * 32;
    const int l15 = lane & 15, q = lane >> 4;
    int aoff[2][4], boff[2][2];
#pragma unroll
    for (int kk = 0; kk < 2; ++kk) {
        int pg = kk * 4 + q;
#pragma unroll
        for (int i = 0; i < 4; ++i) {
            int rm = wm + i * 16 + l15;
            aoff[kk][i] = rm * 64 + ((pg ^ (rm & 7)) * 8);
        }
#pragma unroll
        for (int i = 0; i < 2; ++i) {
            int rn = wn + i * 16 + l15;
            boff[kk][i] = rn * 64 + ((pg ^ (rn & 7)) * 8);
        }
    }

    f32x4 acc[4][2];
#pragma unroll
    for (int i = 0; i < 4; ++i)
#pragma unroll
        for (int j = 0; j < 2; ++j) acc[i][j] = (f32x4){0.f, 0.f, 0.f, 0.f};

    for (int k0 = 0; k0 < K; k0 += 64) {
#pragma unroll
        for (int i = 0; i < 4; ++i) gload_lds16(gA[i] + k0, lA[i]);
#pragma unroll
        for (int i = 0; i < 2; ++i) gload_lds16(gB[i] + k0, lB[i]);
        __syncthreads();
#pragma unroll
        for (int kk = 0; kk < 2; ++kk) {
            bf16x8 af[4], bfr[2];
#pragma unroll
            for (int i = 0; i < 4; ++i) af[i] = *(const bf16x8*)(As + aoff[kk][i]);
#pragma unroll
            for (int i = 0; i < 2; ++i) bfr[i] = *(const bf16x8*)(Bs + boff[kk][i]);
#pragma unroll
            for (int mi = 0; mi < 4; ++mi)
#pragma unroll
                for (int ni = 0; ni < 2; ++ni)
                    acc[mi][ni] = __builtin_amdgcn_mfma_f32_16x16x32_bf16(
                        af[mi], bfr[ni], acc[mi][ni], 0, 0, 0);
        }
        __syncthreads();
    }

    // epilogue: + pos_emb; fused s1/s2 partials; transpose tile; coalesced write
    const float a1v[2] = { a1[n0 + wn + l15], a1[n0 + wn + 16 + l15] };
    const float a2v[2] = { a2[n0 + wn + l15], a2[n0 + wn + 16 + l15] };
#pragma unroll
    for (int mi = 0; mi < 4; ++mi) {
        const int jb = wm + mi * 16 + q * 4;
        float v[2][4];
#pragma unroll
        for (int ni = 0; ni < 2; ++ni) {
            const int nl = wn + ni * 16 + l15;
            ushort4 pk;
            unsigned short* pp = (unsigned short*)&pk;
#pragma unroll
            for (int r = 0; r < 4; ++r) {
                int m = m0 + jb + r;
                int p = pos[m];
                float val = acc[mi][ni][r] + ptab[(size_t)p * DOUT + n0 + nl];
                v[ni][r] = val;
                pp[r] = f2b(val);
            }
            *(ushort4*)&tileT[nl * 136 + jb] = pk;
        }
#pragma unroll
        for (int r = 0; r < 4; ++r) {
            float t1 = v[0][r] * a1v[0] + v[1][r] * a1v[1];
            float t2 = v[0][r] * a2v[0] + v[1][r] * a2v[1];
#pragma unroll
            for (int mk = 1; mk < 16; mk <<= 1) {
                t1 += __shfl_xor(t1, mk);
                t2 += __shfl_xor(t2, mk);
            }
            if (l15 == 0) {
                atomicAdd(&s1[m0 + jb + r], t1);
                atomicAdd(&s2[m0 + jb + r], t2);
            }
        }
    }
    __syncthreads();
    const int bb = m0 >> 9, j0 = m0 & 511;
#pragma unroll
    for (int rr = 0; rr < 4; ++rr) {
        int nl = (t >> 4) + rr * 16;
        int jl = (t & 15) * 8;
        us8 vv = *(const us8*)&tileT[nl * 136 + jl];
        *(us8*)&WhT[((size_t)bb * DOUT + n0 + nl) * N + j0 + jl] = vv;
    }
}

// ---------------------------------------------------------------------------
// Fused softmax + GEMM2.  One block per (b, 64-row m-tile); 512 threads.
// Phase 1: masked softmax for 64 rows (8 lanes/row), writes att fp32 (output)
//          and deposits P bf16 into swizzled LDS (A-operand layout).
// Phase 2: K=512 MFMA loop, B-frags direct from WhT (n-major, L2-resident).
// P LDS layout: addr(r,k) = r*512 + S*8 + (k&7), slot=k>>3,
//               S = slot ^ (r&7) ^ (slot>>3).
// ---------------------------------------------------------------------------
__global__ __launch_bounds__(512) void attn_hp(
    const float* __restrict__ s1,
    const float* __restrict__ s2,
    const int*   __restrict__ adj,
    const unsigned short* __restrict__ WhT,  // [32][256][512]
    float* __restrict__ att,                 // [32][512][512]
    float* __restrict__ hp)                  // [32][512][256]
{
    __shared__ unsigned short P[64 * 512];   // 64 KB

    const int t    = threadIdx.x;
    const int lane = t & 63;
    const int w    = t >> 6;
    const int bb   = blockIdx.x >> 3;
    const int m0   = (blockIdx.x & 7) * 64;

    // ---- phase 1: softmax over 64 rows; 8 threads per row, 64 cols each ----
    {
        const int r = t >> 3, c = t & 7;
        const size_t rowg = (size_t)bb * N + m0 + r;
        const float s1i = s1[rowg];
        const int4*   adjp = (const int4*)(adj + rowg * N + c * 64);
        const float4* s2p  = (const float4*)(s2 + (size_t)bb * N + c * 64);
        float fe[64];
        float mx = -3.0e38f;
#pragma unroll
        for (int i = 0; i < 16; ++i) {
            int4 a = adjp[i];
            float4 sv = s2p[i];
            float v0 = s1i + sv.x; v0 = v0 > 0.f ? v0 : SLOPE * v0; v0 = (a.x > 0) ? v0 : NEGV;
            float v1 = s1i + sv.y; v1 = v1 > 0.f ? v1 : SLOPE * v1; v1 = (a.y > 0) ? v1 : NEGV;
            float v2 = s1i + sv.z; v2 = v2 > 0.f ? v2 : SLOPE * v2; v2 = (a.z > 0) ? v2 : NEGV;
            float v3 = s1i + sv.w; v3 = v3 > 0.f ? v3 : SLOPE * v3; v3 = (a.w > 0) ? v3 : NEGV;
            fe[i * 4 + 0] = v0; fe[i * 4 + 1] = v1;
            fe[i * 4 + 2] = v2; fe[i * 4 + 3] = v3;
            mx = fmaxf(mx, fmaxf(fmaxf(v0, v1), fmaxf(v2, v3)));
        }
#pragma unroll
        for (int mk = 1; mk < 8; mk <<= 1) mx = fmaxf(mx, __shfl_xor(mx, mk));
        float sum = 0.f;
#pragma unroll
        for (int k = 0; k < 64; ++k) { fe[k] = __expf(fe[k] - mx); sum += fe[k]; }
#pragma unroll
        for (int mk = 1; mk < 8; mk <<= 1) sum += __shfl_xor(sum, mk);
        const float inv = 1.0f / sum;

        float* attrow = att + rowg * N + c * 64;
#pragma unroll
        for (int i = 0; i < 16; ++i) {
            float4 o = { fe[i * 4 + 0] * inv, fe[i * 4 + 1] * inv,
                         fe[i * 4 + 2] * inv, fe[i * 4 + 3] * inv };
            ((float4*)attrow)[i] = o;
        }
#pragma unroll
        for (int jj = 0; jj < 8; ++jj) {
            int slot = c * 8 + jj;
            int S = slot ^ (r & 7) ^ c;          // c == slot>>3
            bf16x8 pv;
#pragma unroll
            for (int e = 0; e < 8; ++e) pv[e] = (__bf16)(fe[jj * 8 + e] * inv);
            *(bf16x8*)&P[r * 512 + S * 8] = pv;
        }
    }
    __syncthreads();

    // ---- phase 2: hp[m0..m0+64][0..256] = P @ WhT^T, K = 512 ----
    const int wn  = w * 32;
    const int l15 = lane & 15, q = lane >> 4;
    const unsigned short* bRow[2];
#pragma unroll
    for (int ni = 0; ni < 2; ++ni)
        bRow[ni] = WhT + ((size_t)bb * DOUT + wn + ni * 16 + l15) * N + q * 8;
    int rm7[4], rmBase[4];
#pragma unroll
    for (int mi = 0; mi < 4; ++mi) {
        int rm = mi * 16 + l15;
        rm7[mi] = rm & 7;
        rmBase[mi] = rm * 512;
    }

    f32x4 acc[4][2];
#pragma unroll
    for (int i = 0; i < 4; ++i)
#pragma unroll
        for (int j = 0; j < 2; ++j) acc[i][j] = (f32x4){0.f, 0.f, 0.f, 0.f};

#pragma unroll 4
    for (int k0 = 0; k0 < N; k0 += 32) {
        const int slot = (k0 >> 3) + q;          // 0..63
        const int hi = slot >> 3;
        bf16x8 af[4], bfr[2];
#pragma unroll
        for (int ni = 0; ni < 2; ++ni)
            bfr[ni] = *(const bf16x8*)(bRow[ni] + k0);
#pragma unroll
        for (int mi = 0; mi < 4; ++mi) {
            int S = slot ^ rm7[mi] ^ hi;
            af[mi] = *(const bf16x8*)&P[rmBase[mi] + S * 8];
        }
#pragma unroll
        for (int mi = 0; mi < 4; ++mi)
#pragma unroll
            for (int ni = 0; ni < 2; ++ni)
                acc[mi][ni] = __builtin_amdgcn_mfma_f32_16x16x32_bf16(
                    af[mi], bfr[ni], acc[mi][ni], 0, 0, 0);
    }

#pragma unroll
    for (int mi = 0; mi < 4; ++mi) {
#pragma unroll
        for (int rr = 0; rr < 4; ++rr) {
            int m = m0 + mi * 16 + q * 4 + rr;
#pragma unroll
            for (int ni = 0; ni < 2; ++ni) {
                int n = wn + ni * 16 + l15;
                hp[((size_t)bb * N + m) * DOUT + n] = acc[mi][ni][rr];
            }
        }
    }
}

// ---------------------------------------------------------------------------
extern "C" void kernel_launch(void* const* d_in, const int* in_sizes, int n_in,
                              void* d_out, int out_size, void* d_ws, size_t ws_size,
                              hipStream_t stream) {
    const float* h         = (const float*)d_in[0];
    const int*   adj       = (const int*)  d_in[1];
    const int*   positions = (const int*)  d_in[2];
    const float* W         = (const float*)d_in[3];
    const float* a1        = (const float*)d_in[4];
    const float* a2        = (const float*)d_in[5];
    const float* pos_table = (const float*)d_in[6];

    float* out     = (float*)d_out;
    float* h_prime = out;                           // [B,N,DOUT]
    float* att     = out + (size_t)B * N * DOUT;    // [B,N,N]

    char* ws = (char*)d_ws;
    unsigned short* h_bf = (unsigned short*)ws;                 // 25.2 MB
    unsigned short* WT   = (unsigned short*)(ws + 25165824);    // 0.39 MB
    unsigned short* WhT  = (unsigned short*)(ws + 25559040);    // 8.39 MB
    float*          s1   = (float*)(ws + 33947648);             // 64 KB
    float*          s2   = s1 + (size_t)B * N;

    // 0) zero s1/s2 for the fused atomics
    hipMemsetAsync(s1, 0, (size_t)2 * B * N * sizeof(float), stream);
    // 1) h -> bf16 and W -> WT bf16 (one launch)
    conv_fused<<<12288 + 48, 256, 0, stream>>>((const float4*)h, (ushort4*)h_bf, W, WT);
    // 2) Wh GEMM (LDS-staged BK=64) + pos_emb -> WhT bf16, fused s1/s2
    wh_mfma<<<512, 256, 0, stream>>>(h_bf, WT, positions, pos_table, a1, a2, WhT, s1, s2);
    // 3) fused softmax + h_prime GEMM
    attn_hp<<<256, 512, 0, stream>>>(s1, s2, adj, WhT, att, h_prime);
}

// Round 8
// 171.213 us; speedup vs baseline: 1.2198x; 1.0103x over previous
//
#include <hip/hip_runtime.h>
#include <math.h>

#define B 32
#define N 512
#define DIN 768
#define DOUT 256
#define NEGV -9.0e15f
#define SLOPE 0.2f

typedef __bf16 bf16x8 __attribute__((ext_vector_type(8)));
typedef float f32x4 __attribute__((ext_vector_type(4)));
typedef unsigned short us8 __attribute__((ext_vector_type(8)));   // 16 B

__device__ __forceinline__ unsigned short f2b(float f) {
    union { float f; unsigned u; } v; v.f = f;
    unsigned r = v.u + 0x7FFF + ((v.u >> 16) & 1);
    return (unsigned short)(r >> 16);
}

// async 16B/lane global->LDS; lds ptr wave-uniform (lane i lands at base+i*16)
__device__ __forceinline__ void gload_lds16(const unsigned short* g, unsigned short* l) {
    __builtin_amdgcn_global_load_lds(
        (const __attribute__((address_space(1))) unsigned int*)(unsigned long long)(uintptr_t)g,
        (__attribute__((address_space(3))) unsigned int*)(uintptr_t)l,
        16, 0, 0);
}

// ---------------------------------------------------------------------------
// fused: blocks [0,12288) convert h fp32->bf16 (4/thr);
//        blocks [12288,12336) transpose W -> WT bf16 (64x64 LDS tiles)
// ---------------------------------------------------------------------------
__global__ __launch_bounds__(256) void conv_fused(
    const float4* __restrict__ hin, ushort4* __restrict__ hout,
    const float* __restrict__ W, unsigned short* __restrict__ WT) {
    __shared__ unsigned short tile[64][65];
    const int t = threadIdx.x;
    if (blockIdx.x < 12288) {
        int idx = blockIdx.x * 256 + t;
        float4 v = hin[idx];
        ushort4 o;
        o.x = f2b(v.x); o.y = f2b(v.y); o.z = f2b(v.z); o.w = f2b(v.w);
        hout[idx] = o;
    } else {
        int bid = blockIdx.x - 12288;
        int k0 = (bid % 12) * 64, n0 = (bid / 12) * 64;
        const int cl = t & 63, cg = t >> 6;
#pragma unroll
        for (int i = 0; i < 16; ++i) {
            int k = cg * 16 + i;
            tile[cl][k] = f2b(W[(size_t)(k0 + k) * DOUT + n0 + cl]);
        }
        __syncthreads();
#pragma unroll
        for (int i = 0; i < 16; ++i) {
            int n = cg * 16 + i;
            WT[(size_t)(n0 + n) * DIN + k0 + cl] = tile[n][cl];
        }
    }
}

// ---------------------------------------------------------------------------
// GEMM1: Wh = h @ W + pos_emb -> WhT[b][d][j] bf16 (n-major), fused s1/s2.
// Tile 128m x 64n, BK=64, 256 thr (4 waves). LDS-staged, XOR-swizzled.
// ---------------------------------------------------------------------------
__global__ __launch_bounds__(256) void wh_mfma(
    const unsigned short* __restrict__ hA,   // [16384][768] bf16
    const unsigned short* __restrict__ WT,   // [256][768] bf16
    const int*   __restrict__ pos,           // [16384]
    const float* __restrict__ ptab,          // [512][256]
    const float* __restrict__ a1,
    const float* __restrict__ a2,
    unsigned short* __restrict__ WhT,        // [32][256][512]
    float* __restrict__ s1, float* __restrict__ s2)
{
    constexpr int K = DIN;
    __shared__ unsigned short smem[12288];
    unsigned short* As = smem;
    unsigned short* Bs = smem + 8192;
    unsigned short* tileT = smem;            // reused after k-loop

    const int t    = threadIdx.x;
    const int lane = t & 63;
    const int w    = t >> 6;
    const int lin  = blockIdx.x;
    const int m0   = (lin & 127) * 128;
    const int n0   = (lin >> 7) * 64;

    int arow[4], apos[4];
#pragma unroll
    for (int i = 0; i < 4; ++i) {
        int c = i * 256 + t;
        arow[i] = c >> 3;
        apos[i] = (c & 7) ^ ((c >> 3) & 7);
    }
    int brow[2], bpos[2];
#pragma unroll
    for (int i = 0; i < 2; ++i) {
        int c = i * 256 + t;
        brow[i] = c >> 3;
        bpos[i] = (c & 7) ^ ((c >> 3) & 7);
    }
    const unsigned short* gA[4];
    const unsigned short* gB[2];
#pragma unroll
    for (int i = 0; i < 4; ++i) gA[i] = hA + (size_t)(m0 + arow[i]) * K + apos[i] * 8;
#pragma unroll
    for (int i = 0; i < 2; ++i) gB[i] = WT + (size_t)(n0 + brow[i]) * K + bpos[i] * 8;
    unsigned short* lA[4];
    unsigned short* lB[2];
#pragma unroll
    for (int i = 0; i < 4; ++i) lA[i] = As + (i * 256 + (t & 192)) * 8;
#pragma unroll
    for (int i = 0; i < 2; ++i) lB[i] = Bs + (i * 256 + (t & 192)) * 8;

    const int wm = (w & 1) * 64, wn = (w >> 1) * 32;
    const int l15 = lane & 15, q = lane >> 4;
    int aoff[2][4], boff[2][2];
#pragma unroll
    for (int kk = 0; kk < 2; ++kk) {
        int pg = kk * 4 + q;
#pragma unroll
        for (int i = 0; i < 4; ++i) {
            int rm = wm + i * 16 + l15;
            aoff[kk][i] = rm * 64 + ((pg ^ (rm & 7)) * 8);
        }
#pragma unroll
        for (int i = 0; i < 2; ++i) {
            int rn = wn + i * 16 + l15;
            boff[kk][i] = rn * 64 + ((pg ^ (rn & 7)) * 8);
        }
    }

    f32x4 acc[4][2];
#pragma unroll
    for (int i = 0; i < 4; ++i)
#pragma unroll
        for (int j = 0; j < 2; ++j) acc[i][j] = (f32x4){0.f, 0.f, 0.f, 0.f};

    for (int k0 = 0; k0 < K; k0 += 64) {
#pragma unroll
        for (int i = 0; i < 4; ++i) gload_lds16(gA[i] + k0, lA[i]);
#pragma unroll
        for (int i = 0; i < 2; ++i) gload_lds16(gB[i] + k0, lB[i]);
        __syncthreads();
#pragma unroll
        for (int kk = 0; kk < 2; ++kk) {
            bf16x8 af[4], bfr[2];
#pragma unroll
            for (int i = 0; i < 4; ++i) af[i] = *(const bf16x8*)(As + aoff[kk][i]);
#pragma unroll
            for (int i = 0; i < 2; ++i) bfr[i] = *(const bf16x8*)(Bs + boff[kk][i]);
#pragma unroll
            for (int mi = 0; mi < 4; ++mi)
#pragma unroll
                for (int ni = 0; ni < 2; ++ni)
                    acc[mi][ni] = __builtin_amdgcn_mfma_f32_16x16x32_bf16(
                        af[mi], bfr[ni], acc[mi][ni], 0, 0, 0);
        }
        __syncthreads();
    }

    // epilogue: + pos_emb; fused s1/s2 partials; transpose tile; coalesced write
    const float a1v[2] = { a1[n0 + wn + l15], a1[n0 + wn + 16 + l15] };
    const float a2v[2] = { a2[n0 + wn + l15], a2[n0 + wn + 16 + l15] };
#pragma unroll
    for (int mi = 0; mi < 4; ++mi) {
        const int jb = wm + mi * 16 + q * 4;
        float v[2][4];
#pragma unroll
        for (int ni = 0; ni < 2; ++ni) {
            const int nl = wn + ni * 16 + l15;
            ushort4 pk;
            unsigned short* pp = (unsigned short*)&pk;
#pragma unroll
            for (int r = 0; r < 4; ++r) {
                int m = m0 + jb + r;
                int p = pos[m];
                float val = acc[mi][ni][r] + ptab[(size_t)p * DOUT + n0 + nl];
                v[ni][r] = val;
                pp[r] = f2b(val);
            }
            *(ushort4*)&tileT[nl * 136 + jb] = pk;
        }
#pragma unroll
        for (int r = 0; r < 4; ++r) {
            float t1 = v[0][r] * a1v[0] + v[1][r] * a1v[1];
            float t2 = v[0][r] * a2v[0] + v[1][r] * a2v[1];
#pragma unroll
            for (int mk = 1; mk < 16; mk <<= 1) {
                t1 += __shfl_xor(t1, mk);
                t2 += __shfl_xor(t2, mk);
            }
            if (l15 == 0) {
                atomicAdd(&s1[m0 + jb + r], t1);
                atomicAdd(&s2[m0 + jb + r], t2);
            }
        }
    }
    __syncthreads();
    const int bb = m0 >> 9, j0 = m0 & 511;
#pragma unroll
    for (int rr = 0; rr < 4; ++rr) {
        int nl = (t >> 4) + rr * 16;
        int jl = (t & 15) * 8;
        us8 vv = *(const us8*)&tileT[nl * 136 + jl];
        *(us8*)&WhT[((size_t)bb * DOUT + n0 + nl) * N + j0 + jl] = vv;
    }
}

// ---------------------------------------------------------------------------
// Fused softmax + GEMM2.  One block per (b, 64-row m-tile); 512 threads.
// Phase 1 (NO per-thread array; 3 recompute passes, adj packed to a 64-bit
// mask): 8 threads/row, cols j = i*32 + c*4 (+0..3) -> lane-contiguous loads.
// Phase 2: K=512 MFMA loop, B-frags direct from WhT (n-major, L2-resident).
// P LDS layout: addr(r,j) with slot=j>>3, S = slot ^ (r&7) ^ (slot>>3),
//               addr = r*512 + S*8 + (j&7).
// ---------------------------------------------------------------------------
__global__ __launch_bounds__(512) void attn_hp(
    const float* __restrict__ s1,
    const float* __restrict__ s2,
    const int*   __restrict__ adj,
    const unsigned short* __restrict__ WhT,  // [32][256][512]
    float* __restrict__ att,                 // [32][512][512]
    float* __restrict__ hp)                  // [32][512][256]
{
    __shared__ unsigned short P[64 * 512];   // 64 KB

    const int t    = threadIdx.x;
    const int lane = t & 63;
    const int w    = t >> 6;
    const int bb   = blockIdx.x >> 3;
    const int m0   = (blockIdx.x & 7) * 64;

    // ---- phase 1: masked softmax, 8 threads/row, 64 cols each ----
    {
        const int r = t >> 3, c = t & 7;
        const size_t rowg = (size_t)bb * N + m0 + r;
        const float s1i = s1[rowg];
        const int4*   adjp = (const int4*)(adj + rowg * N) + c;       // [i*8]
        const float4* s2p  = (const float4*)(s2 + (size_t)bb * N) + c;

        // pass 1: adj -> 64-bit mask; masked max
        unsigned long long msk = 0ull;
        float mx = -3.0e38f;
#pragma unroll 4
        for (int i = 0; i < 16; ++i) {
            int4 a = adjp[i * 8];
            float4 sv = s2p[i * 8];
            float v0 = s1i + sv.x; v0 = v0 > 0.f ? v0 : SLOPE * v0;
            float v1 = s1i + sv.y; v1 = v1 > 0.f ? v1 : SLOPE * v1;
            float v2 = s1i + sv.z; v2 = v2 > 0.f ? v2 : SLOPE * v2;
            float v3 = s1i + sv.w; v3 = v3 > 0.f ? v3 : SLOPE * v3;
            v0 = (a.x > 0) ? v0 : NEGV;
            v1 = (a.y > 0) ? v1 : NEGV;
            v2 = (a.z > 0) ? v2 : NEGV;
            v3 = (a.w > 0) ? v3 : NEGV;
            unsigned bits = (a.x > 0 ? 1u : 0u) | (a.y > 0 ? 2u : 0u) |
                            (a.z > 0 ? 4u : 0u) | (a.w > 0 ? 8u : 0u);
            msk |= (unsigned long long)bits << (i * 4);
            mx = fmaxf(mx, fmaxf(fmaxf(v0, v1), fmaxf(v2, v3)));
        }
#pragma unroll
        for (int mk = 1; mk < 8; mk <<= 1) mx = fmaxf(mx, __shfl_xor(mx, mk));

        // pass 2: recompute, sum of exp
        float sum = 0.f;
#pragma unroll 4
        for (int i = 0; i < 16; ++i) {
            float4 sv = s2p[i * 8];
            float v0 = s1i + sv.x; v0 = v0 > 0.f ? v0 : SLOPE * v0;
            float v1 = s1i + sv.y; v1 = v1 > 0.f ? v1 : SLOPE * v1;
            float v2 = s1i + sv.z; v2 = v2 > 0.f ? v2 : SLOPE * v2;
            float v3 = s1i + sv.w; v3 = v3 > 0.f ? v3 : SLOPE * v3;
            v0 = ((msk >> (i * 4 + 0)) & 1) ? v0 : NEGV;
            v1 = ((msk >> (i * 4 + 1)) & 1) ? v1 : NEGV;
            v2 = ((msk >> (i * 4 + 2)) & 1) ? v2 : NEGV;
            v3 = ((msk >> (i * 4 + 3)) & 1) ? v3 : NEGV;
            sum += __expf(v0 - mx) + __expf(v1 - mx) +
                   __expf(v2 - mx) + __expf(v3 - mx);
        }
#pragma unroll
        for (int mk = 1; mk < 8; mk <<= 1) sum += __shfl_xor(sum, mk);
        const float inv = 1.0f / sum;

        // pass 3: recompute, write att fp32 + P bf16 (swizzled)
        float4* attrow = (float4*)(att + rowg * N);
        unsigned short* Prow = P + r * 512;
        const int r7 = r & 7, chalf = (c & 1) * 4;
#pragma unroll 4
        for (int i = 0; i < 16; ++i) {
            float4 sv = s2p[i * 8];
            float v0 = s1i + sv.x; v0 = v0 > 0.f ? v0 : SLOPE * v0;
            float v1 = s1i + sv.y; v1 = v1 > 0.f ? v1 : SLOPE * v1;
            float v2 = s1i + sv.z; v2 = v2 > 0.f ? v2 : SLOPE * v2;
            float v3 = s1i + sv.w; v3 = v3 > 0.f ? v3 : SLOPE * v3;
            v0 = ((msk >> (i * 4 + 0)) & 1) ? v0 : NEGV;
            v1 = ((msk >> (i * 4 + 1)) & 1) ? v1 : NEGV;
            v2 = ((msk >> (i * 4 + 2)) & 1) ? v2 : NEGV;
            v3 = ((msk >> (i * 4 + 3)) & 1) ? v3 : NEGV;
            float e0 = __expf(v0 - mx) * inv;
            float e1 = __expf(v1 - mx) * inv;
            float e2 = __expf(v2 - mx) * inv;
            float e3 = __expf(v3 - mx) * inv;
            attrow[i * 8 + c] = (float4){e0, e1, e2, e3};
            int slot = i * 4 + (c >> 1);
            int S = slot ^ r7 ^ (slot >> 3);
            ushort4 pk = { f2b(e0), f2b(e1), f2b(e2), f2b(e3) };
            *(ushort4*)&Prow[S * 8 + chalf] = pk;
        }
    }
    __syncthreads();

    // ---- phase 2: hp[m0..m0+64][0..256] = P @ WhT^T, K = 512 ----
    const int wn  = w * 32;
    const int l15 = lane & 15, q = lane >> 4;
    const unsigned short* bRow[2];
#pragma unroll
    for (int ni = 0; ni < 2; ++ni)
        bRow[ni] = WhT + ((size_t)bb * DOUT + wn + ni * 16 + l15) * N + q * 8;
    int rm7[4], rmBase[4];
#pragma unroll
    for (int mi = 0; mi < 4; ++mi) {
        int rm = mi * 16 + l15;
        rm7[mi] = rm & 7;
        rmBase[mi] = rm * 512;
    }

    f32x4 acc[4][2];
#pragma unroll
    for (int i = 0; i < 4; ++i)
#pragma unroll
        for (int j = 0; j < 2; ++j) acc[i][j] = (f32x4){0.f, 0.f, 0.f, 0.f};

#pragma unroll 4
    for (int k0 = 0; k0 < N; k0 += 32) {
        const int slot = (k0 >> 3) + q;          // 0..63
        const int hi = slot >> 3;
        bf16x8 af[4], bfr[2];
#pragma unroll
        for (int ni = 0; ni < 2; ++ni)
            bfr[ni] = *(const bf16x8*)(bRow[ni] + k0);
#pragma unroll
        for (int mi = 0; mi < 4; ++mi) {
            int S = slot ^ rm7[mi] ^ hi;
            af[mi] = *(const bf16x8*)&P[rmBase[mi] + S * 8];
        }
#pragma unroll
        for (int mi = 0; mi < 4; ++mi)
#pragma unroll
            for (int ni = 0; ni < 2; ++ni)
                acc[mi][ni] = __builtin_amdgcn_mfma_f32_16x16x32_bf16(
                    af[mi], bfr[ni], acc[mi][ni], 0, 0, 0);
    }

#pragma unroll
    for (int mi = 0; mi < 4; ++mi) {
#pragma unroll
        for (int rr = 0; rr < 4; ++rr) {
            int m = m0 + mi * 16 + q * 4 + rr;
#pragma unroll
            for (int ni = 0; ni < 2; ++ni) {
                int n = wn + ni * 16 + l15;
                hp[((size_t)bb * N + m) * DOUT + n] = acc[mi][ni][rr];
            }
        }
    }
}

// ---------------------------------------------------------------------------
extern "C" void kernel_launch(void* const* d_in, const int* in_sizes, int n_in,
                              void* d_out, int out_size, void* d_ws, size_t ws_size,
                              hipStream_t stream) {
    const float* h         = (const float*)d_in[0];
    const int*   adj       = (const int*)  d_in[1];
    const int*   positions = (const int*)  d_in[2];
    const float* W         = (const float*)d_in[3];
    const float* a1        = (const float*)d_in[4];
    const float* a2        = (const float*)d_in[5];
    const float* pos_table = (const float*)d_in[6];

    float* out     = (float*)d_out;
    float* h_prime = out;                           // [B,N,DOUT]
    float* att     = out + (size_t)B * N * DOUT;    // [B,N,N]

    char* ws = (char*)d_ws;
    unsigned short* h_bf = (unsigned short*)ws;                 // 25.2 MB
    unsigned short* WT   = (unsigned short*)(ws + 25165824);    // 0.39 MB
    unsigned short* WhT  = (unsigned short*)(ws + 25559040);    // 8.39 MB
    float*          s1   = (float*)(ws + 33947648);             // 64 KB
    float*          s2   = s1 + (size_t)B * N;

    // 0) zero s1/s2 for the fused atomics
    hipMemsetAsync(s1, 0, (size_t)2 * B * N * sizeof(float), stream);
    // 1) h -> bf16 and W -> WT bf16 (one launch)
    conv_fused<<<12288 + 48, 256, 0, stream>>>((const float4*)h, (ushort4*)h_bf, W, WT);
    // 2) Wh GEMM (LDS-staged BK=64) + pos_emb -> WhT bf16, fused s1/s2
    wh_mfma<<<512, 256, 0, stream>>>(h_bf, WT, positions, pos_table, a1, a2, WhT, s1, s2);
    // 3) fused softmax + h_prime GEMM (spill-free phase 1)
    attn_hp<<<256, 512, 0, stream>>>(s1, s2, adj, WhT, att, h_prime);
}